// Round 5
// baseline (175.426 us; speedup 1.0000x reference)
//
#include <hip/hip_runtime.h>
#include <hip/hip_bf16.h>

typedef unsigned short u16;
typedef unsigned int u32;
typedef u16 u16x4 __attribute__((ext_vector_type(4)));
typedef u16 u16x8 __attribute__((ext_vector_type(8)));
typedef u32 u32x4 __attribute__((ext_vector_type(4)));
typedef __bf16 bf16x8 __attribute__((ext_vector_type(8)));
typedef float f32x4 __attribute__((ext_vector_type(4)));

__device__ __forceinline__ u16 f2bf(float f) {
  union { float f; unsigned u; } v; v.f = f;
  unsigned r = v.u + 0x7fffu + ((v.u >> 16) & 1u);
  return (u16)(r >> 16);
}

__device__ __forceinline__ u16 bf(float f) {
  __bf16 h = (__bf16)f;
  union { __bf16 h; u16 u; } c; c.h = h;
  return c.u;
}

__device__ __forceinline__ u32 pack2(float lo, float hi) {
  return (u32)bf(lo) | ((u32)bf(hi) << 16);
}

__device__ __forceinline__ float fexp2(float x) {
#if __has_builtin(__builtin_amdgcn_exp2f)
  return __builtin_amdgcn_exp2f(x);
#else
  return exp2f(x);
#endif
}

__device__ __forceinline__ float frcp(float x) {
#if __has_builtin(__builtin_amdgcn_rcpf)
  return __builtin_amdgcn_rcpf(x);
#else
  return 1.0f / x;
#endif
}

__device__ __forceinline__ void gload16(const void* g, void* l) {
  __builtin_amdgcn_global_load_lds((const __attribute__((address_space(1))) void*)g,
                                   (__attribute__((address_space(3))) void*)l, 16, 0, 0);
}

// ---------------- f32 -> bf16 elementwise ----------------
__global__ __launch_bounds__(256) void cvt_bf16(const float* __restrict__ in,
                                                u16* __restrict__ out, int n) {
  int i = (blockIdx.x * 256 + threadIdx.x) * 8;
  if (i >= n) return;
  f32x4 a = *(const f32x4*)(in + i);
  f32x4 b = *(const f32x4*)(in + i + 4);
  u16x8 r;
  r[0] = f2bf(a[0]); r[1] = f2bf(a[1]); r[2] = f2bf(a[2]); r[3] = f2bf(a[3]);
  r[4] = f2bf(b[0]); r[5] = f2bf(b[1]); r[6] = f2bf(b[2]); r[7] = f2bf(b[3]);
  *(u16x8*)(out + i) = r;
}

// ------------- transpose+convert: in [K][N] f32 -> out [N][K] bf16 -------------
__global__ __launch_bounds__(256) void transpose_cvt(const float* __restrict__ in,
                                                     u16* __restrict__ out,
                                                     int K, int N) {
  __shared__ float tile[32][33];
  int n0 = blockIdx.x * 32, k0 = blockIdx.y * 32;
  int tx = threadIdx.x & 31, ty = threadIdx.x >> 5;
  for (int i = 0; i < 32; i += 8)
    tile[ty + i][tx] = in[(long)(k0 + ty + i) * N + n0 + tx];
  __syncthreads();
  for (int i = 0; i < 32; i += 8)
    out[(long)(n0 + ty + i) * K + k0 + tx] = f2bf(tile[tx][ty + i]);
}

// ------------- GEMM: C[M][N] = A[M][K] * Bt[N][K]^T (+bias) -------------
template<int BM, int BN, bool F32OUT>
__global__ __launch_bounds__(256) void gemm_bt(
    const u16* __restrict__ A, const u16* __restrict__ Bt,
    void* __restrict__ Cp, const float* __restrict__ bias,
    int M, int N, int K)
{
  constexpr int MR = BM / 32, NR = BN / 32;
  constexpr int RA = BM / 64, RB = BN / 64;
  __shared__ char lds[(BM + BN) * 64];
  char* As = lds;
  char* Bs = lds + BM * 64;
  const int tid = threadIdx.x;
  const int l = tid & 63, w = tid >> 6;
  const int wr = w >> 1, wc = w & 1;
  const int lr = l & 15, q4 = l >> 4;
  const long row0 = (long)blockIdx.x * BM;
  const long col0 = (long)blockIdx.y * BN;

  f32x4 acc[MR][NR] = {};

  const u16* gA[RA];
  int oA[RA];
  for (int i = 0; i < RA; ++i) {
    int o = i * 4096 + tid * 16;
    int r = o >> 6, c = ((o >> 4) & 3) ^ (r & 3);
    oA[i] = o;
    gA[i] = A + (row0 + r) * K + c * 8;
  }
  const u16* gB[RB];
  int oB[RB];
  for (int i = 0; i < RB; ++i) {
    int o = i * 4096 + tid * 16;
    int r = o >> 6, c = ((o >> 4) & 3) ^ (r & 3);
    oB[i] = o;
    gB[i] = Bt + (col0 + r) * K + c * 8;
  }

  for (int k0 = 0; k0 < K; k0 += 32) {
    __syncthreads();
    for (int i = 0; i < RA; ++i) gload16(gA[i] + k0, As + oA[i]);
    for (int i = 0; i < RB; ++i) gload16(gB[i] + k0, Bs + oB[i]);
    __syncthreads();
    bf16x8 a[MR], b[NR];
    for (int m = 0; m < MR; ++m) {
      int r = wr * (BM / 2) + m * 16 + lr;
      a[m] = *(const bf16x8*)(As + r * 64 + ((q4 ^ (r & 3)) << 4));
    }
    for (int n = 0; n < NR; ++n) {
      int r = wc * (BN / 2) + n * 16 + lr;
      b[n] = *(const bf16x8*)(Bs + r * 64 + ((q4 ^ (r & 3)) << 4));
    }
    for (int m = 0; m < MR; ++m)
      for (int n = 0; n < NR; ++n)
        acc[m][n] = __builtin_amdgcn_mfma_f32_16x16x32_bf16(a[m], b[n], acc[m][n], 0, 0, 0);
  }

  for (int n = 0; n < NR; ++n) {
    int col = (int)col0 + wc * (BN / 2) + n * 16 + lr;
    float bv = 0.f;
    if (F32OUT) bv = bias[col];
    for (int m = 0; m < MR; ++m) {
      for (int reg = 0; reg < 4; ++reg) {
        long row = row0 + wr * (BM / 2) + m * 16 + q4 * 4 + reg;
        float vv = acc[m][n][reg] + bv;
        if (F32OUT) ((float*)Cp)[row * N + col] = vv;
        else        ((u16*)Cp)[row * N + col] = f2bf(vv);
      }
    }
  }
}

// ------------- causal flash attention (swapped QK^T, in-register softmax) ----
// qkv [B*T][3072] bf16. atty [B*T][1024] bf16.
// Block: 64 q-rows (4 waves x 16), KV tiles of 64, K/V double-buffered.
// S^T = mfma(K,Q): lane (lr,q4) holds S[key = k0+n*16+q4*4+reg][q = wrow+lr]
// -> all 16 values share one q-row: scalar m/l, 2-step shfl reduces, P stays
// in regs and is re-shuffled into the PV B-fragment (no P LDS).
#define FXOR(d) (((((d) & 7) ^ (((d) >> 3) & 7))) << 4)

__global__ __launch_bounds__(256) void attn_fwd(
    const u16* __restrict__ qkv, u16* __restrict__ atty)
{
  __shared__ char ksmem[2 * 8192];
  __shared__ char vtmem[2 * 8192];      // Vt[d][key], XOR-swizzled rows
  const int tid = threadIdx.x;
  const int l = tid & 63, w = tid >> 6;
  const int lr = l & 15, q4 = l >> 4;
  const int h = blockIdx.y;
  const int qb = blockIdx.z ? (31 - (int)blockIdx.x) : (int)blockIdx.x;
  const int q0 = qb * 64;
  const long base = (long)blockIdx.z * 2048;
  const int wrow = q0 + w * 16;

  // Q fragment (B-operand): lane holds Q[q=wrow+lr][k=kk*32+q4*8..], pre-scaled
  bf16x8 qf[2];
  for (int kk = 0; kk < 2; ++kk) {
    u16x8 raw = *(const u16x8*)(qkv + (base + wrow + lr) * 3072 + h * 64 + kk * 32 + q4 * 8);
    u16x8 sc;
    for (int j = 0; j < 8; ++j) {
      union { unsigned u; float f; } c; c.u = ((unsigned)raw[j]) << 16;
      sc[j] = bf(c.f * 0.18033688f);   // 0.125 * log2(e)
    }
    qf[kk] = *(bf16x8*)&sc;
  }

  float mrun = -__builtin_inff(), lsum = 0.f;
  f32x4 o[4] = {};

  // K staging: 2x 16B global_load_lds per thread (rows 0-31, 32-63)
  const int r0 = tid >> 3, c0 = (tid & 7) ^ (r0 & 7);
  const int r1 = 32 + (tid >> 3), c1 = (tid & 7) ^ (r1 & 7);
  const u16* kg0 = qkv + (base + r0) * 3072 + 1024 + h * 64 + c0 * 8;
  const u16* kg1 = qkv + (base + r1) * 3072 + 1024 + h * 64 + c1 * 8;
  // V: thread loads key pair (va, va+1) x 8 d's; writes 8x b32 (conflict-free)
  const int va = (tid & 31) * 2, vd0 = (tid >> 5) * 8;
  const u16* vg = qkv + (base + va) * 3072 + 2048 + h * 64 + vd0;

  const int nkv = qb + 1;

  // prologue: stage tile 0 into buffer 0
  {
    u16x8 v0a = *(const u16x8*)(vg);
    u16x8 v0b = *(const u16x8*)(vg + 3072);
    gload16(kg0, ksmem + tid * 16);
    gload16(kg1, ksmem + 4096 + tid * 16);
    for (int j = 0; j < 8; ++j) {
      int d = vd0 + j;
      *(u32*)(vtmem + d * 128 + ((va * 2) ^ FXOR(d))) = (u32)v0a[j] | ((u32)v0b[j] << 16);
    }
  }
  __syncthreads();

  for (int t = 0; t < nkv; ++t) {
    const int cur = t & 1;
    const int k0 = t * 64;
    char* ks = ksmem + cur * 8192;
    char* vt = vtmem + cur * 8192;
    const bool more = (t + 1) < nkv;
    u16x8 vna, vnb;
    if (more) {
      long off = (long)(t + 1) * 64 * 3072;
      vna = *(const u16x8*)(vg + off);
      vnb = *(const u16x8*)(vg + off + 3072);
      gload16(kg0 + off, ksmem + (cur ^ 1) * 8192 + tid * 16);
      gload16(kg1 + off, ksmem + (cur ^ 1) * 8192 + 4096 + tid * 16);
    }

    // S^T = K Q^T: st[n][reg] = S[key=k0+n*16+q4*4+reg][q=wrow+lr]
    f32x4 st[4] = {};
    __builtin_amdgcn_s_setprio(1);
    for (int kk = 0; kk < 2; ++kk)
      for (int n = 0; n < 4; ++n) {
        int r = n * 16 + lr;
        int c = (kk * 4 + q4) ^ (r & 7);
        bf16x8 kf = *(const bf16x8*)(ks + r * 128 + (c << 4));
        st[n] = __builtin_amdgcn_mfma_f32_16x16x32_bf16(kf, qf[kk], st[n], 0, 0, 0);
      }
    __builtin_amdgcn_s_setprio(0);

    // causal mask: only last tile (t == qb); key_off > 16*w + lr masks
    if (t == qb) {
      for (int n = 0; n < 4; ++n)
        for (int reg = 0; reg < 4; ++reg)
          if (n * 16 + q4 * 4 + reg > 16 * w + lr)
            st[n][reg] = -__builtin_inff();
    }

    // row max: lane-local over 16, then across q4 lanes (xor 16, 32)
    float pm = fmaxf(fmaxf(fmaxf(st[0][0], st[0][1]), fmaxf(st[0][2], st[0][3])),
                     fmaxf(fmaxf(st[1][0], st[1][1]), fmaxf(st[1][2], st[1][3])));
    pm = fmaxf(pm, fmaxf(fmaxf(fmaxf(st[2][0], st[2][1]), fmaxf(st[2][2], st[2][3])),
                         fmaxf(fmaxf(st[3][0], st[3][1]), fmaxf(st[3][2], st[3][3]))));
    pm = fmaxf(pm, __shfl_xor(pm, 16));
    pm = fmaxf(pm, __shfl_xor(pm, 32));

    // defer-max rescale
    if (__any(pm > mrun + 8.f)) {
      float mn = fmaxf(mrun, pm);
      float scl = fexp2(mrun - mn);
      mrun = mn;
      lsum *= scl;
      for (int n = 0; n < 4; ++n)
        for (int reg = 0; reg < 4; ++reg) o[n][reg] *= scl;
    }

    // P = exp2(S - m); pack to bf16 pairs; accumulate row sum
    float psum = 0.f;
    u32 pk[4][2];
    for (int n = 0; n < 4; ++n) {
      float p0 = fexp2(st[n][0] - mrun), p1 = fexp2(st[n][1] - mrun);
      float p2 = fexp2(st[n][2] - mrun), p3 = fexp2(st[n][3] - mrun);
      psum += (p0 + p1) + (p2 + p3);
      pk[n][0] = pack2(p0, p1);
      pk[n][1] = pack2(p2, p3);
    }
    psum += __shfl_xor(psum, 16);
    psum += __shfl_xor(psum, 32);
    lsum += psum;

    // redistribute P^T into PV B-fragments and accumulate O
    for (int kk = 0; kk < 2; ++kk) {
      const int n0 = kk * 2, n1 = kk * 2 + 1;
      const bool hi = (q4 >> 1) != 0;
      u32 ys0 = hi ? pk[n1][0] : pk[n0][0];
      u32 ys1 = hi ? pk[n1][1] : pk[n0][1];
      u32 yc0 = hi ? pk[n0][0] : pk[n1][0];
      u32 yc1 = hi ? pk[n0][1] : pk[n1][1];
      u32 t16_0 = __shfl_xor(ys0, 16), t16_1 = __shfl_xor(ys1, 16);
      u32 t32_0 = __shfl_xor(yc0, 32), t32_1 = __shfl_xor(yc1, 32);
      u32 t48_0 = __shfl_xor(yc0, 48), t48_1 = __shfl_xor(yc1, 48);
      u32x4 pb;
      pb[0] = q4 == 0 ? ys0 : q4 == 1 ? t48_0 : q4 == 2 ? t32_0 : t16_0;
      pb[1] = q4 == 0 ? ys1 : q4 == 1 ? t48_1 : q4 == 2 ? t32_1 : t16_1;
      pb[2] = q4 == 0 ? t16_0 : q4 == 1 ? t32_0 : q4 == 2 ? t48_0 : ys0;
      pb[3] = q4 == 0 ? t16_1 : q4 == 1 ? t32_1 : q4 == 2 ? t48_1 : ys1;
      bf16x8 pf = *(bf16x8*)&pb;
      __builtin_amdgcn_s_setprio(1);
      for (int n = 0; n < 4; ++n) {
        int dd = n * 16 + lr;
        bf16x8 vf = *(const bf16x8*)(vt + dd * 128 + ((kk * 64 + q4 * 16) ^ FXOR(dd)));
        o[n] = __builtin_amdgcn_mfma_f32_16x16x32_bf16(vf, pf, o[n], 0, 0, 0);
      }
      __builtin_amdgcn_s_setprio(0);
    }

    if (more) {
      char* vtn = vtmem + (cur ^ 1) * 8192;
      for (int j = 0; j < 8; ++j) {
        int d = vd0 + j;
        *(u32*)(vtn + d * 128 + ((va * 2) ^ FXOR(d))) = (u32)vna[j] | ((u32)vnb[j] << 16);
      }
      __syncthreads();   // drains K DMA + publishes V for tile t+1
    }
  }

  // epilogue: normalize, pack 4 bf16 (consecutive d), 8B coalesced stores
  float inv = frcp(lsum);
  long row = base + wrow + lr;
  for (int n = 0; n < 4; ++n) {
    u16x4 ov;
    for (int reg = 0; reg < 4; ++reg) ov[reg] = bf(o[n][reg] * inv);
    *(u16x4*)(atty + row * 1024 + h * 64 + n * 16 + q4 * 4) = ov;
  }
}

extern "C" void kernel_launch(void* const* d_in, const int* in_sizes, int n_in,
                              void* d_out, int out_size, void* d_ws, size_t ws_size,
                              hipStream_t stream) {
  const float* x     = (const float*)d_in[0];
  const float* Wqkv  = (const float*)d_in[1];
  const float* Wproj = (const float*)d_in[2];
  const float* bproj = (const float*)d_in[3];
  char* ws = (char*)d_ws;
  u16* xb   = (u16*)(ws);                    // 4096*1024 bf16      (8 MB)
  u16* wqT  = (u16*)(ws + 8388608);          // [3072][1024] bf16   (6 MB)
  u16* wpT  = (u16*)(ws + 14680064);         // [1024][1024] bf16   (2 MB)
  u16* qkv  = (u16*)(ws + 16777216);         // [4096][3072] bf16   (24 MB)
  u16* atty = (u16*)(ws + 41943040);         // [4096][1024] bf16   (8 MB)

  cvt_bf16<<<2048, 256, 0, stream>>>(x, xb, 4194304);
  transpose_cvt<<<dim3(96, 32), 256, 0, stream>>>(Wqkv, wqT, 1024, 3072);
  transpose_cvt<<<dim3(32, 32), 256, 0, stream>>>(Wproj, wpT, 1024, 1024);
  gemm_bt<128, 128, false><<<dim3(32, 24), 256, 0, stream>>>(xb, wqT, (void*)qkv, nullptr, 4096, 3072, 1024);
  attn_fwd<<<dim3(32, 16, 2), 256, 0, stream>>>(qkv, atty);
  gemm_bt<128, 64, true><<<dim3(32, 16), 256, 0, stream>>>(atty, wpT, d_out, bproj, 4096, 1024, 1024);
}

// Round 6
// 129.203 us; speedup vs baseline: 1.3578x; 1.3578x over previous
//
#include <hip/hip_runtime.h>
#include <hip/hip_bf16.h>

typedef unsigned short u16;
typedef unsigned int u32;
typedef u16 u16x4 __attribute__((ext_vector_type(4)));
typedef u16 u16x8 __attribute__((ext_vector_type(8)));
typedef u32 u32x4 __attribute__((ext_vector_type(4)));
typedef __bf16 bf16x8 __attribute__((ext_vector_type(8)));
typedef float f32x4 __attribute__((ext_vector_type(4)));

__device__ __forceinline__ u16 f2bf(float f) {
  union { float f; unsigned u; } v; v.f = f;
  unsigned r = v.u + 0x7fffu + ((v.u >> 16) & 1u);
  return (u16)(r >> 16);
}

__device__ __forceinline__ u16 bf(float f) {
  __bf16 h = (__bf16)f;
  union { __bf16 h; u16 u; } c; c.h = h;
  return c.u;
}

__device__ __forceinline__ u32 pack2(float lo, float hi) {
  return (u32)bf(lo) | ((u32)bf(hi) << 16);
}

__device__ __forceinline__ float fexp2(float x) {
#if __has_builtin(__builtin_amdgcn_exp2f)
  return __builtin_amdgcn_exp2f(x);
#else
  return exp2f(x);
#endif
}

__device__ __forceinline__ float frcp(float x) {
#if __has_builtin(__builtin_amdgcn_rcpf)
  return __builtin_amdgcn_rcpf(x);
#else
  return 1.0f / x;
#endif
}

__device__ __forceinline__ void gload16(const void* g, void* l) {
  __builtin_amdgcn_global_load_lds((const __attribute__((address_space(1))) void*)g,
                                   (__attribute__((address_space(3))) void*)l, 16, 0, 0);
}

// ---------------- f32 -> bf16 elementwise ----------------
__global__ __launch_bounds__(256) void cvt_bf16(const float* __restrict__ in,
                                                u16* __restrict__ out, int n) {
  int i = (blockIdx.x * 256 + threadIdx.x) * 8;
  if (i >= n) return;
  f32x4 a = *(const f32x4*)(in + i);
  f32x4 b = *(const f32x4*)(in + i + 4);
  u16x8 r;
  r[0] = f2bf(a[0]); r[1] = f2bf(a[1]); r[2] = f2bf(a[2]); r[3] = f2bf(a[3]);
  r[4] = f2bf(b[0]); r[5] = f2bf(b[1]); r[6] = f2bf(b[2]); r[7] = f2bf(b[3]);
  *(u16x8*)(out + i) = r;
}

// ------------- transpose+convert: in [K][N] f32 -> out [N][K] bf16 -------------
__global__ __launch_bounds__(256) void transpose_cvt(const float* __restrict__ in,
                                                     u16* __restrict__ out,
                                                     int K, int N) {
  __shared__ float tile[32][33];
  int n0 = blockIdx.x * 32, k0 = blockIdx.y * 32;
  int tx = threadIdx.x & 31, ty = threadIdx.x >> 5;
  for (int i = 0; i < 32; i += 8)
    tile[ty + i][tx] = in[(long)(k0 + ty + i) * N + n0 + tx];
  __syncthreads();
  for (int i = 0; i < 32; i += 8)
    out[(long)(n0 + ty + i) * K + k0 + tx] = f2bf(tile[tx][ty + i]);
}

// ------------- GEMM: C[M][N] = A[M][K] * Bt[N][K]^T (+bias) -------------
template<int BM, int BN, bool F32OUT>
__global__ __launch_bounds__(256) void gemm_bt(
    const u16* __restrict__ A, const u16* __restrict__ Bt,
    void* __restrict__ Cp, const float* __restrict__ bias,
    int M, int N, int K)
{
  constexpr int MR = BM / 32, NR = BN / 32;
  constexpr int RA = BM / 64, RB = BN / 64;
  __shared__ char lds[(BM + BN) * 64];
  char* As = lds;
  char* Bs = lds + BM * 64;
  const int tid = threadIdx.x;
  const int l = tid & 63, w = tid >> 6;
  const int wr = w >> 1, wc = w & 1;
  const int lr = l & 15, q4 = l >> 4;
  const long row0 = (long)blockIdx.x * BM;
  const long col0 = (long)blockIdx.y * BN;

  f32x4 acc[MR][NR] = {};

  const u16* gA[RA];
  int oA[RA];
  for (int i = 0; i < RA; ++i) {
    int o = i * 4096 + tid * 16;
    int r = o >> 6, c = ((o >> 4) & 3) ^ (r & 3);
    oA[i] = o;
    gA[i] = A + (row0 + r) * K + c * 8;
  }
  const u16* gB[RB];
  int oB[RB];
  for (int i = 0; i < RB; ++i) {
    int o = i * 4096 + tid * 16;
    int r = o >> 6, c = ((o >> 4) & 3) ^ (r & 3);
    oB[i] = o;
    gB[i] = Bt + (col0 + r) * K + c * 8;
  }

  for (int k0 = 0; k0 < K; k0 += 32) {
    __syncthreads();
    for (int i = 0; i < RA; ++i) gload16(gA[i] + k0, As + oA[i]);
    for (int i = 0; i < RB; ++i) gload16(gB[i] + k0, Bs + oB[i]);
    __syncthreads();
    bf16x8 a[MR], b[NR];
    for (int m = 0; m < MR; ++m) {
      int r = wr * (BM / 2) + m * 16 + lr;
      a[m] = *(const bf16x8*)(As + r * 64 + ((q4 ^ (r & 3)) << 4));
    }
    for (int n = 0; n < NR; ++n) {
      int r = wc * (BN / 2) + n * 16 + lr;
      b[n] = *(const bf16x8*)(Bs + r * 64 + ((q4 ^ (r & 3)) << 4));
    }
    for (int m = 0; m < MR; ++m)
      for (int n = 0; n < NR; ++n)
        acc[m][n] = __builtin_amdgcn_mfma_f32_16x16x32_bf16(a[m], b[n], acc[m][n], 0, 0, 0);
  }

  for (int n = 0; n < NR; ++n) {
    int col = (int)col0 + wc * (BN / 2) + n * 16 + lr;
    float bv = 0.f;
    if (F32OUT) bv = bias[col];
    for (int m = 0; m < MR; ++m) {
      for (int reg = 0; reg < 4; ++reg) {
        long row = row0 + wr * (BM / 2) + m * 16 + q4 * 4 + reg;
        float vv = acc[m][n][reg] + bv;
        if (F32OUT) ((float*)Cp)[row * N + col] = vv;
        else        ((u16*)Cp)[row * N + col] = f2bf(vv);
      }
    }
  }
}

// ------------- causal flash attention -------------
// Swapped QK^T (S^T = mfma(K,Q)) with in-register softmax; V stored in LDS
// with key-PERMUTED columns so the PV B-fragment is the lane's own P regs
// (zero shuffles). 512 thr / 8 waves / 128 q-rows per block; KV tiles of 64,
// double-buffered. qb flipped by batch for causal balance.
// V column permutation: key = n*16+g*4+r  ->  col' = (n>>1)*32+g*8+(n&1)*4+r
#define FXOR(d) (((((d) & 7) ^ (((d) >> 3) & 7))) << 4)

__global__ __launch_bounds__(512) void attn_fwd(
    const u16* __restrict__ qkv, u16* __restrict__ atty)
{
  __shared__ char ksmem[2 * 8192];
  __shared__ char vtmem[2 * 8192];      // Vt[d][col'], XOR-swizzled rows
  const int tid = threadIdx.x;
  const int l = tid & 63, w = tid >> 6;
  const int lr = l & 15, g = l >> 4;
  const int h = blockIdx.y;
  const int qb = blockIdx.z ? (15 - (int)blockIdx.x) : (int)blockIdx.x;
  const int q0 = qb * 128;
  const long base = (long)blockIdx.z * 2048;
  const int wrow = q0 + w * 16;

  // Q fragment (B-operand): lane holds Q[q=wrow+lr][k=kk*32+g*8..], pre-scaled
  bf16x8 qf[2];
  for (int kk = 0; kk < 2; ++kk) {
    u16x8 raw = *(const u16x8*)(qkv + (base + wrow + lr) * 3072 + h * 64 + kk * 32 + g * 8);
    u16x8 sc;
    for (int j = 0; j < 8; ++j) {
      union { unsigned u; float f; } c; c.u = ((unsigned)raw[j]) << 16;
      sc[j] = bf(c.f * 0.18033688f);   // 0.125 * log2(e)
    }
    qf[kk] = *(bf16x8*)&sc;
  }

  float mrun = -__builtin_inff(), lsum = 0.f;
  f32x4 o[4] = {};

  // K staging: one 16B global_load_lds per thread (512 chunks = 64 rows x 128B)
  const int kr = tid >> 3, kc = (tid & 7) ^ (kr & 7);
  const u16* kg = qkv + (base + kr) * 3072 + 1024 + h * 64 + kc * 8;
  // V staging (tid<256): key-pair (2a,2a+1) x 8 d's; u32 writes, permuted cols
  const int va = tid & 31;              // key pair index
  const int vd0 = ((tid >> 5) & 7) * 8; // d group
  const int vn = va >> 3, vg = (va >> 1) & 3, vr = (va & 1) * 2;
  const int vcol2 = ((vn >> 1) * 32 + vg * 8 + (vn & 1) * 4 + vr) * 2; // byte off
  const u16* vgp = qkv + (base + va * 2) * 3072 + 2048 + h * 64 + vd0;

  const int nkv = 2 * qb + 2;

  // prologue: stage tile 0 into buffer 0
  {
    u16x8 v0a, v0b;
    if (tid < 256) {
      v0a = *(const u16x8*)(vgp);
      v0b = *(const u16x8*)(vgp + 3072);
    }
    gload16(kg, ksmem + tid * 16);
    if (tid < 256) {
      for (int j = 0; j < 8; ++j) {
        int d = vd0 + j;
        *(u32*)(vtmem + d * 128 + (vcol2 ^ FXOR(d))) = (u32)v0a[j] | ((u32)v0b[j] << 16);
      }
    }
  }
  __syncthreads();

  for (int t = 0; t < nkv; ++t) {
    const int cur = t & 1;
    const int k0 = t * 64;
    char* ks = ksmem + cur * 8192;
    char* vt = vtmem + cur * 8192;
    const bool more = (t + 1) < nkv;
    u16x8 vna, vnb;
    if (more) {
      long off = (long)(t + 1) * 64 * 3072;
      if (tid < 256) {
        vna = *(const u16x8*)(vgp + off);
        vnb = *(const u16x8*)(vgp + off + 3072);
      }
      gload16(kg + off, ksmem + (cur ^ 1) * 8192 + tid * 16);
    }

    if (k0 <= wrow + 15) {
      // S^T = K Q^T: st[n][reg] = S[key=k0+n*16+g*4+reg][q=wrow+lr]
      f32x4 st[4] = {};
      __builtin_amdgcn_s_setprio(1);
      for (int kk = 0; kk < 2; ++kk)
        for (int n = 0; n < 4; ++n) {
          int r = n * 16 + lr;
          int c = (kk * 4 + g) ^ (r & 7);
          bf16x8 kf = *(const bf16x8*)(ks + r * 128 + (c << 4));
          st[n] = __builtin_amdgcn_mfma_f32_16x16x32_bf16(kf, qf[kk], st[n], 0, 0, 0);
        }
      __builtin_amdgcn_s_setprio(0);

      // causal mask on the partially-masked (diagonal) tiles
      if (k0 + 63 > wrow) {
        for (int n = 0; n < 4; ++n)
          for (int reg = 0; reg < 4; ++reg)
            if (k0 + n * 16 + g * 4 + reg > wrow + lr)
              st[n][reg] = -__builtin_inff();
      }

      // row max: lane-local over 16 keys, then across g-lanes (xor 16, 32)
      float pm = fmaxf(fmaxf(fmaxf(st[0][0], st[0][1]), fmaxf(st[0][2], st[0][3])),
                       fmaxf(fmaxf(st[1][0], st[1][1]), fmaxf(st[1][2], st[1][3])));
      pm = fmaxf(pm, fmaxf(fmaxf(fmaxf(st[2][0], st[2][1]), fmaxf(st[2][2], st[2][3])),
                           fmaxf(fmaxf(st[3][0], st[3][1]), fmaxf(st[3][2], st[3][3]))));
      pm = fmaxf(pm, __shfl_xor(pm, 16));
      pm = fmaxf(pm, __shfl_xor(pm, 32));

      // defer-max rescale
      if (__any(pm > mrun + 8.f)) {
        float mn = fmaxf(mrun, pm);
        float scl = fexp2(mrun - mn);
        mrun = mn;
        lsum *= scl;
        for (int n = 0; n < 4; ++n)
          for (int reg = 0; reg < 4; ++reg) o[n][reg] *= scl;
      }

      // P = exp2(S - m), packed to bf16 pairs (these ARE the PV B-fragments)
      float psum = 0.f;
      u32 pk[4][2];
      for (int n = 0; n < 4; ++n) {
        float p0 = fexp2(st[n][0] - mrun), p1 = fexp2(st[n][1] - mrun);
        float p2 = fexp2(st[n][2] - mrun), p3 = fexp2(st[n][3] - mrun);
        psum += (p0 + p1) + (p2 + p3);
        pk[n][0] = pack2(p0, p1);
        pk[n][1] = pack2(p2, p3);
      }
      psum += __shfl_xor(psum, 16);
      psum += __shfl_xor(psum, 32);
      lsum += psum;

      // O^T += V^T P^T ; B-fragment = lane's own pk (key-permuted V storage)
      __builtin_amdgcn_s_setprio(1);
      for (int kt = 0; kt < 2; ++kt) {
        u32x4 pb;
        pb[0] = pk[2 * kt][0];
        pb[1] = pk[2 * kt][1];
        pb[2] = pk[2 * kt + 1][0];
        pb[3] = pk[2 * kt + 1][1];
        bf16x8 pf = *(bf16x8*)&pb;
        for (int n = 0; n < 4; ++n) {
          int dd = n * 16 + lr;
          bf16x8 vf = *(const bf16x8*)(vt + dd * 128 + ((kt * 64 + g * 16) ^ FXOR(dd)));
          o[n] = __builtin_amdgcn_mfma_f32_16x16x32_bf16(vf, pf, o[n], 0, 0, 0);
        }
      }
      __builtin_amdgcn_s_setprio(0);
    }

    if (more) {
      if (tid < 256) {
        char* vtn = vtmem + (cur ^ 1) * 8192;
        for (int j = 0; j < 8; ++j) {
          int d = vd0 + j;
          *(u32*)(vtn + d * 128 + (vcol2 ^ FXOR(d))) = (u32)vna[j] | ((u32)vnb[j] << 16);
        }
      }
      __syncthreads();   // drains K DMA + publishes V for tile t+1
    }
  }

  // epilogue: normalize, pack 4 bf16 (consecutive d), 8B coalesced stores
  float inv = frcp(lsum);
  long row = base + wrow + lr;
  for (int n = 0; n < 4; ++n) {
    u16x4 ov;
    for (int reg = 0; reg < 4; ++reg) ov[reg] = bf(o[n][reg] * inv);
    *(u16x4*)(atty + row * 1024 + h * 64 + n * 16 + g * 4) = ov;
  }
}

extern "C" void kernel_launch(void* const* d_in, const int* in_sizes, int n_in,
                              void* d_out, int out_size, void* d_ws, size_t ws_size,
                              hipStream_t stream) {
  const float* x     = (const float*)d_in[0];
  const float* Wqkv  = (const float*)d_in[1];
  const float* Wproj = (const float*)d_in[2];
  const float* bproj = (const float*)d_in[3];
  char* ws = (char*)d_ws;
  u16* xb   = (u16*)(ws);                    // 4096*1024 bf16      (8 MB)
  u16* wqT  = (u16*)(ws + 8388608);          // [3072][1024] bf16   (6 MB)
  u16* wpT  = (u16*)(ws + 14680064);         // [1024][1024] bf16   (2 MB)
  u16* qkv  = (u16*)(ws + 16777216);         // [4096][3072] bf16   (24 MB)
  u16* atty = (u16*)(ws + 41943040);         // [4096][1024] bf16   (8 MB)

  cvt_bf16<<<2048, 256, 0, stream>>>(x, xb, 4194304);
  transpose_cvt<<<dim3(96, 32), 256, 0, stream>>>(Wqkv, wqT, 1024, 3072);
  transpose_cvt<<<dim3(32, 32), 256, 0, stream>>>(Wproj, wpT, 1024, 1024);
  gemm_bt<128, 128, false><<<dim3(32, 24), 256, 0, stream>>>(xb, wqT, (void*)qkv, nullptr, 4096, 3072, 1024);
  attn_fwd<<<dim3(16, 16, 2), 512, 0, stream>>>(qkv, atty);
  gemm_bt<128, 64, true><<<dim3(32, 16), 256, 0, stream>>>(atty, wpT, d_out, bproj, 4096, 1024, 1024);
}

// Round 7
// 125.159 us; speedup vs baseline: 1.4016x; 1.0323x over previous
//
#include <hip/hip_runtime.h>
#include <hip/hip_bf16.h>

typedef unsigned short u16;
typedef unsigned int u32;
typedef u16 u16x4 __attribute__((ext_vector_type(4)));
typedef u16 u16x8 __attribute__((ext_vector_type(8)));
typedef u32 u32x4 __attribute__((ext_vector_type(4)));
typedef __bf16 bf16x8 __attribute__((ext_vector_type(8)));
typedef float f32x4 __attribute__((ext_vector_type(4)));

__device__ __forceinline__ u16 f2bf(float f) {
  union { float f; unsigned u; } v; v.f = f;
  unsigned r = v.u + 0x7fffu + ((v.u >> 16) & 1u);
  return (u16)(r >> 16);
}

__device__ __forceinline__ u16 bf(float f) {
  __bf16 h = (__bf16)f;
  union { __bf16 h; u16 u; } c; c.h = h;
  return c.u;
}

__device__ __forceinline__ u32 pack2(float lo, float hi) {
  return (u32)bf(lo) | ((u32)bf(hi) << 16);
}

__device__ __forceinline__ float fexp2(float x) {
#if __has_builtin(__builtin_amdgcn_exp2f)
  return __builtin_amdgcn_exp2f(x);
#else
  return exp2f(x);
#endif
}

__device__ __forceinline__ float frcp(float x) {
#if __has_builtin(__builtin_amdgcn_rcpf)
  return __builtin_amdgcn_rcpf(x);
#else
  return 1.0f / x;
#endif
}

__device__ __forceinline__ void gload16(const void* g, void* l) {
  __builtin_amdgcn_global_load_lds((const __attribute__((address_space(1))) void*)g,
                                   (__attribute__((address_space(3))) void*)l, 16, 0, 0);
}

// ---------------- f32 -> bf16 elementwise ----------------
__global__ __launch_bounds__(256) void cvt_bf16(const float* __restrict__ in,
                                                u16* __restrict__ out, int n) {
  int i = (blockIdx.x * 256 + threadIdx.x) * 8;
  if (i >= n) return;
  f32x4 a = *(const f32x4*)(in + i);
  f32x4 b = *(const f32x4*)(in + i + 4);
  u16x8 r;
  r[0] = f2bf(a[0]); r[1] = f2bf(a[1]); r[2] = f2bf(a[2]); r[3] = f2bf(a[3]);
  r[4] = f2bf(b[0]); r[5] = f2bf(b[1]); r[6] = f2bf(b[2]); r[7] = f2bf(b[3]);
  *(u16x8*)(out + i) = r;
}

// ------------- transpose+convert: in [K][N] f32 -> out [N][K] bf16 -------------
__global__ __launch_bounds__(256) void transpose_cvt(const float* __restrict__ in,
                                                     u16* __restrict__ out,
                                                     int K, int N) {
  __shared__ float tile[32][33];
  int n0 = blockIdx.x * 32, k0 = blockIdx.y * 32;
  int tx = threadIdx.x & 31, ty = threadIdx.x >> 5;
  for (int i = 0; i < 32; i += 8)
    tile[ty + i][tx] = in[(long)(k0 + ty + i) * N + n0 + tx];
  __syncthreads();
  for (int i = 0; i < 32; i += 8)
    out[(long)(n0 + ty + i) * K + k0 + tx] = f2bf(tile[tx][ty + i]);
}

// ------------- GEMM: C[M][N] = A[M][K] * Bt[N][K]^T (+bias) -------------
template<int BM, int BN, bool F32OUT>
__global__ __launch_bounds__(256) void gemm_bt(
    const u16* __restrict__ A, const u16* __restrict__ Bt,
    void* __restrict__ Cp, const float* __restrict__ bias,
    int M, int N, int K)
{
  constexpr int MR = BM / 32, NR = BN / 32;
  constexpr int RA = BM / 64, RB = BN / 64;
  __shared__ char lds[(BM + BN) * 64];
  char* As = lds;
  char* Bs = lds + BM * 64;
  const int tid = threadIdx.x;
  const int l = tid & 63, w = tid >> 6;
  const int wr = w >> 1, wc = w & 1;
  const int lr = l & 15, q4 = l >> 4;
  const long row0 = (long)blockIdx.x * BM;
  const long col0 = (long)blockIdx.y * BN;

  f32x4 acc[MR][NR] = {};

  const u16* gA[RA];
  int oA[RA];
  for (int i = 0; i < RA; ++i) {
    int o = i * 4096 + tid * 16;
    int r = o >> 6, c = ((o >> 4) & 3) ^ (r & 3);
    oA[i] = o;
    gA[i] = A + (row0 + r) * K + c * 8;
  }
  const u16* gB[RB];
  int oB[RB];
  for (int i = 0; i < RB; ++i) {
    int o = i * 4096 + tid * 16;
    int r = o >> 6, c = ((o >> 4) & 3) ^ (r & 3);
    oB[i] = o;
    gB[i] = Bt + (col0 + r) * K + c * 8;
  }

  for (int k0 = 0; k0 < K; k0 += 32) {
    __syncthreads();
    for (int i = 0; i < RA; ++i) gload16(gA[i] + k0, As + oA[i]);
    for (int i = 0; i < RB; ++i) gload16(gB[i] + k0, Bs + oB[i]);
    __syncthreads();
    bf16x8 a[MR], b[NR];
    for (int m = 0; m < MR; ++m) {
      int r = wr * (BM / 2) + m * 16 + lr;
      a[m] = *(const bf16x8*)(As + r * 64 + ((q4 ^ (r & 3)) << 4));
    }
    for (int n = 0; n < NR; ++n) {
      int r = wc * (BN / 2) + n * 16 + lr;
      b[n] = *(const bf16x8*)(Bs + r * 64 + ((q4 ^ (r & 3)) << 4));
    }
    for (int m = 0; m < MR; ++m)
      for (int n = 0; n < NR; ++n)
        acc[m][n] = __builtin_amdgcn_mfma_f32_16x16x32_bf16(a[m], b[n], acc[m][n], 0, 0, 0);
  }

  for (int n = 0; n < NR; ++n) {
    int col = (int)col0 + wc * (BN / 2) + n * 16 + lr;
    float bv = 0.f;
    if (F32OUT) bv = bias[col];
    for (int m = 0; m < MR; ++m) {
      for (int reg = 0; reg < 4; ++reg) {
        long row = row0 + wr * (BM / 2) + m * 16 + q4 * 4 + reg;
        float vv = acc[m][n][reg] + bv;
        if (F32OUT) ((float*)Cp)[row * N + col] = vv;
        else        ((u16*)Cp)[row * N + col] = f2bf(vv);
      }
    }
  }
}

// ------------- causal flash attention -------------
// Swapped QK^T (S^T = mfma(K,Q)), in-register softmax, key-permuted V (PV
// B-fragment = lane's own P regs). WORK-BALANCED blocks: each block owns two
// 64-row q-tiles {i, 31-i}: waves 0-3 -> tile i, waves 4-7 -> tile 31-i.
// Compute per block = (i+1)+(32-i) = 33 KV-tiles for EVERY block -> any
// block->CU assignment is balanced. KV double-buffered; lsum reduce deferred
// to epilogue (per-lane partials; rescale is row-uniform so linear).
// V column permutation: key = n*16+g*4+r -> col' = (n>>1)*32+g*8+(n&1)*4+r
#define FXOR(d) (((((d) & 7) ^ (((d) >> 3) & 7))) << 4)

__global__ __launch_bounds__(512) void attn_fwd(
    const u16* __restrict__ qkv, u16* __restrict__ atty)
{
  __shared__ char ksmem[2 * 8192];
  __shared__ char vtmem[2 * 8192];      // Vt[d][col'], XOR-swizzled rows
  const int tid = threadIdx.x;
  const int l = tid & 63, w = tid >> 6;
  const int lr = l & 15, g = l >> 4;
  const int h = blockIdx.y;
  const int ti = blockIdx.x;            // pair index 0..15
  const long base = (long)blockIdx.z * 2048;
  // waves 0-3: q-tile ti (rows 64*ti..); waves 4-7: q-tile 31-ti
  const int wrow = (w < 4) ? (ti * 64 + w * 16) : ((31 - ti) * 64 + (w - 4) * 16);

  // Q fragment (B-operand): lane holds Q[q=wrow+lr][k=kk*32+g*8..], pre-scaled
  bf16x8 qf[2];
  for (int kk = 0; kk < 2; ++kk) {
    u16x8 raw = *(const u16x8*)(qkv + (base + wrow + lr) * 3072 + h * 64 + kk * 32 + g * 8);
    u16x8 sc;
    for (int j = 0; j < 8; ++j) {
      union { unsigned u; float f; } c; c.u = ((unsigned)raw[j]) << 16;
      sc[j] = bf(c.f * 0.18033688f);   // 0.125 * log2(e)
    }
    qf[kk] = *(bf16x8*)&sc;
  }

  float mrun = -__builtin_inff(), lsum = 0.f;   // lsum = PER-LANE partial
  f32x4 o[4] = {};

  // K staging: one 16B global_load_lds per thread (512 chunks = 64 rows x 128B)
  const int kr = tid >> 3, kc = (tid & 7) ^ (kr & 7);
  const u16* kg = qkv + (base + kr) * 3072 + 1024 + h * 64 + kc * 8;
  // V staging: all 512 threads; key-pair (2a,2a+1) x 4 d's; u32 writes
  const int va = tid >> 4;              // key-pair index 0..31
  const int vd0 = (tid & 15) * 4;       // d group (lanes consecutive in d)
  const int vk0 = va * 2;
  const int vn = vk0 >> 4, vgp2 = (vk0 >> 2) & 3, vr = vk0 & 3;
  const int vcol2 = ((vn >> 1) * 32 + vgp2 * 8 + (vn & 1) * 4 + vr) * 2; // byte
  const u16* vgp = qkv + (base + vk0) * 3072 + 2048 + h * 64 + vd0;

  const int nkv = 32 - ti;              // KV range of the hi tile

  // prologue: stage tile 0 into buffer 0
  {
    u16x4 v0a = *(const u16x4*)(vgp);
    u16x4 v0b = *(const u16x4*)(vgp + 3072);
    gload16(kg, ksmem + tid * 16);
    for (int j = 0; j < 4; ++j) {
      int d = vd0 + j;
      *(u32*)(vtmem + d * 128 + (vcol2 ^ FXOR(d))) = (u32)v0a[j] | ((u32)v0b[j] << 16);
    }
  }
  __syncthreads();

  for (int t = 0; t < nkv; ++t) {
    const int cur = t & 1;
    const int k0 = t * 64;
    char* ks = ksmem + cur * 8192;
    char* vt = vtmem + cur * 8192;
    const bool more = (t + 1) < nkv;
    u16x4 vna, vnb;
    if (more) {
      long off = (long)(t + 1) * 64 * 3072;
      vna = *(const u16x4*)(vgp + off);
      vnb = *(const u16x4*)(vgp + off + 3072);
      gload16(kg + off, ksmem + (cur ^ 1) * 8192 + tid * 16);
    }

    if (k0 <= wrow + 15) {
      // S^T = K Q^T: st[n][reg] = S[key=k0+n*16+g*4+reg][q=wrow+lr]
      f32x4 st[4] = {};
      __builtin_amdgcn_s_setprio(1);
      for (int kk = 0; kk < 2; ++kk)
        for (int n = 0; n < 4; ++n) {
          int r = n * 16 + lr;
          int c = (kk * 4 + g) ^ (r & 7);
          bf16x8 kf = *(const bf16x8*)(ks + r * 128 + (c << 4));
          st[n] = __builtin_amdgcn_mfma_f32_16x16x32_bf16(kf, qf[kk], st[n], 0, 0, 0);
        }
      __builtin_amdgcn_s_setprio(0);

      // causal mask on the partially-masked (diagonal) tiles
      if (k0 + 63 > wrow) {
        for (int n = 0; n < 4; ++n)
          for (int reg = 0; reg < 4; ++reg)
            if (k0 + n * 16 + g * 4 + reg > wrow + lr)
              st[n][reg] = -__builtin_inff();
      }

      // row max: lane-local over 16 keys, then across g-lanes (xor 16, 32)
      float pm = fmaxf(fmaxf(fmaxf(st[0][0], st[0][1]), fmaxf(st[0][2], st[0][3])),
                       fmaxf(fmaxf(st[1][0], st[1][1]), fmaxf(st[1][2], st[1][3])));
      pm = fmaxf(pm, fmaxf(fmaxf(fmaxf(st[2][0], st[2][1]), fmaxf(st[2][2], st[2][3])),
                           fmaxf(fmaxf(st[3][0], st[3][1]), fmaxf(st[3][2], st[3][3]))));
      pm = fmaxf(pm, __shfl_xor(pm, 16));
      pm = fmaxf(pm, __shfl_xor(pm, 32));

      // defer-max rescale
      if (__any(pm > mrun + 8.f)) {
        float mn = fmaxf(mrun, pm);
        float scl = fexp2(mrun - mn);
        mrun = mn;
        lsum *= scl;
        for (int n = 0; n < 4; ++n)
          for (int reg = 0; reg < 4; ++reg) o[n][reg] *= scl;
      }

      // P = exp2(S - m), packed to bf16 pairs (these ARE the PV B-fragments)
      float psum = 0.f;
      u32 pk[4][2];
      for (int n = 0; n < 4; ++n) {
        float p0 = fexp2(st[n][0] - mrun), p1 = fexp2(st[n][1] - mrun);
        float p2 = fexp2(st[n][2] - mrun), p3 = fexp2(st[n][3] - mrun);
        psum += (p0 + p1) + (p2 + p3);
        pk[n][0] = pack2(p0, p1);
        pk[n][1] = pack2(p2, p3);
      }
      lsum += psum;                     // per-lane partial; reduce at epilogue

      // O^T += V^T P^T ; B-fragment = lane's own pk (key-permuted V storage)
      __builtin_amdgcn_s_setprio(1);
      for (int kt = 0; kt < 2; ++kt) {
        u32x4 pb;
        pb[0] = pk[2 * kt][0];
        pb[1] = pk[2 * kt][1];
        pb[2] = pk[2 * kt + 1][0];
        pb[3] = pk[2 * kt + 1][1];
        bf16x8 pf = *(bf16x8*)&pb;
        for (int n = 0; n < 4; ++n) {
          int dd = n * 16 + lr;
          bf16x8 vf = *(const bf16x8*)(vt + dd * 128 + ((kt * 64 + g * 16) ^ FXOR(dd)));
          o[n] = __builtin_amdgcn_mfma_f32_16x16x32_bf16(vf, pf, o[n], 0, 0, 0);
        }
      }
      __builtin_amdgcn_s_setprio(0);
    }

    if (more) {
      char* vtn = vtmem + (cur ^ 1) * 8192;
      for (int j = 0; j < 4; ++j) {
        int d = vd0 + j;
        *(u32*)(vtn + d * 128 + (vcol2 ^ FXOR(d))) = (u32)vna[j] | ((u32)vnb[j] << 16);
      }
      __syncthreads();   // drains K DMA + publishes V for tile t+1
    }
  }

  // epilogue: reduce lsum across g-lanes, normalize, 8B coalesced stores
  lsum += __shfl_xor(lsum, 16);
  lsum += __shfl_xor(lsum, 32);
  float inv = frcp(lsum);
  long row = base + wrow + lr;
  for (int n = 0; n < 4; ++n) {
    u16x4 ov;
    for (int reg = 0; reg < 4; ++reg) ov[reg] = bf(o[n][reg] * inv);
    *(u16x4*)(atty + row * 1024 + h * 64 + n * 16 + g * 4) = ov;
  }
}

extern "C" void kernel_launch(void* const* d_in, const int* in_sizes, int n_in,
                              void* d_out, int out_size, void* d_ws, size_t ws_size,
                              hipStream_t stream) {
  const float* x     = (const float*)d_in[0];
  const float* Wqkv  = (const float*)d_in[1];
  const float* Wproj = (const float*)d_in[2];
  const float* bproj = (const float*)d_in[3];
  char* ws = (char*)d_ws;
  u16* xb   = (u16*)(ws);                    // 4096*1024 bf16      (8 MB)
  u16* wqT  = (u16*)(ws + 8388608);          // [3072][1024] bf16   (6 MB)
  u16* wpT  = (u16*)(ws + 14680064);         // [1024][1024] bf16   (2 MB)
  u16* qkv  = (u16*)(ws + 16777216);         // [4096][3072] bf16   (24 MB)
  u16* atty = (u16*)(ws + 41943040);         // [4096][1024] bf16   (8 MB)

  cvt_bf16<<<2048, 256, 0, stream>>>(x, xb, 4194304);
  transpose_cvt<<<dim3(96, 32), 256, 0, stream>>>(Wqkv, wqT, 1024, 3072);
  transpose_cvt<<<dim3(32, 32), 256, 0, stream>>>(Wproj, wpT, 1024, 1024);
  gemm_bt<128, 128, false><<<dim3(32, 24), 256, 0, stream>>>(xb, wqT, (void*)qkv, nullptr, 4096, 3072, 1024);
  attn_fwd<<<dim3(16, 16, 2), 512, 0, stream>>>(qkv, atty);
  gemm_bt<128, 64, true><<<dim3(32, 16), 256, 0, stream>>>(atty, wpT, d_out, bproj, 4096, 1024, 1024);
}